// Round 6
// baseline (353.329 us; speedup 1.0000x reference)
//
#include <hip/hip_runtime.h>

#define N_NODES  50000
#define N_EDGES  800000
#define N_GRAPHS 128
#define HD       128
#define K2       256
#define CLS      10
#define NPART    8
#define PSIZE    (N_NODES / NPART)          // 6250
#define NSUB     16
#define NB_SCAN  ((N_NODES + 255) / 256)    // 196
#define NBIN     1600
#define CHUNK    (N_EDGES / NBIN)           // 500
#define PCAP     131072
#define NSLOT    16

typedef __attribute__((ext_vector_type(8))) _Float16 f16x8;
typedef __attribute__((ext_vector_type(4))) float f32x4;
typedef __attribute__((ext_vector_type(2))) float f32x2;

union U4H8 { uint4 u; _Float16 h[8]; };
union U2H4 { uint2 u; _Float16 h[4]; };

typedef const __attribute__((address_space(1))) void* gptr_t;
typedef __attribute__((address_space(3))) void* lptr_t;
#define GLOAD_LDS16(g, l) \
    __builtin_amdgcn_global_load_lds((gptr_t)(g), (lptr_t)(l), 16, 0, 0)

// ---------------- zero gcount(8) + bflag(256), adjacent ----------------
__global__ __launch_bounds__(512) void k_zero(int* __restrict__ z) {
    int i = threadIdx.x;
    if (i < 264) z[i] = 0;
}

// ---------------- bin edges by dst partition (LDS histogram + packed staging) ----------------
__global__ __launch_bounds__(256) void k_bin(const int* __restrict__ src, const int* __restrict__ dst,
                                             unsigned* __restrict__ stag, int* __restrict__ gcount) {
    __shared__ int lcount[NPART];
    __shared__ int lbase[NPART];
    const int tid = threadIdx.x;
    const int lo = blockIdx.x * CHUNK;
    if (tid < NPART) lcount[tid] = 0;
    __syncthreads();
    int dc[2], sc[2];
#pragma unroll
    for (int it = 0; it < 2; ++it) {
        int i = lo + tid + it * 256;
        dc[it] = -1;
        if (i < lo + CHUNK) {
            int d = dst[i];
            dc[it] = d; sc[it] = src[i];
            atomicAdd(&lcount[d / PSIZE], 1);
        }
    }
    __syncthreads();
    if (tid < NPART) {
        lbase[tid] = atomicAdd(&gcount[tid], lcount[tid]);
        lcount[tid] = 0;   // reuse as cursor
    }
    __syncthreads();
#pragma unroll
    for (int it = 0; it < 2; ++it) {
        if (dc[it] >= 0) {
            int p = dc[it] / PSIZE;
            int slot = atomicAdd(&lcount[p], 1);
            stag[(size_t)p * PCAP + lbase[p] + slot] =
                (unsigned)sc[it] | ((unsigned)(dc[it] - p * PSIZE) << 16);
        }
    }
}

// ---------------- hist: per-(partition, 1/16-edge-chunk) LDS histogram -> global plane ----------------
__global__ __launch_bounds__(512) void k_hist(const unsigned* __restrict__ stag,
                                              const int* __restrict__ gcount,
                                              int* __restrict__ ghist) {
    __shared__ int hist[PSIZE];
    const int tid = threadIdx.x;
    const int p = blockIdx.x & (NPART - 1);
    const int s = blockIdx.x >> 3;
    for (int j = tid; j < PSIZE; j += 512) hist[j] = 0;
    __syncthreads();
    const int n = gcount[p];
    const int cs = (int)(((long long)s * n) / NSUB);
    const int ce = (int)(((long long)(s + 1) * n) / NSUB);
    const unsigned* sp = stag + (size_t)p * PCAP;
    for (int i = cs + tid; i < ce; i += 512)
        atomicAdd(&hist[sp[i] >> 16], 1);
    __syncthreads();
    int* gh = ghist + (size_t)blockIdx.x * PSIZE;
    for (int j = tid; j < PSIZE; j += 512) gh[j] = hist[j];
}

// ---------------- scan: deg = sum of 16 planes; rowptr via decoupled lookback; planes -> cursors ----------------
__global__ __launch_bounds__(256) void k_scan(int* __restrict__ ghist,
                                              int* __restrict__ rowptr,
                                              int* __restrict__ bsum, int* __restrict__ bflag) {
    __shared__ int sc[256];
    __shared__ int r[256];
    const int tid = threadIdx.x;
    const int b = blockIdx.x;
    const int node = b * 256 + tid;
    int d[NSUB];
    int deg = 0, p = 0, off = 0;
    if (node < N_NODES) {
        p = node / PSIZE; off = node - p * PSIZE;
#pragma unroll
        for (int s = 0; s < NSUB; ++s) {
            d[s] = ghist[(size_t)(s * NPART + p) * PSIZE + off];
            deg += d[s];
        }
    }
    sc[tid] = deg;
    __syncthreads();
    for (int o = 1; o < 256; o <<= 1) {
        int add = (tid >= o) ? sc[tid - o] : 0;
        __syncthreads();
        sc[tid] += add;
        __syncthreads();
    }
    if (tid == 255) {
        __hip_atomic_store(&bsum[b], sc[255], __ATOMIC_RELAXED, __HIP_MEMORY_SCOPE_AGENT);
        __hip_atomic_store(&bflag[b], 1, __ATOMIC_RELEASE, __HIP_MEMORY_SCOPE_AGENT);
    }
    int agg = 0;
    if (tid < b) {
        while (__hip_atomic_load(&bflag[tid], __ATOMIC_ACQUIRE, __HIP_MEMORY_SCOPE_AGENT) == 0) {}
        agg = __hip_atomic_load(&bsum[tid], __ATOMIC_RELAXED, __HIP_MEMORY_SCOPE_AGENT);
    }
    r[tid] = agg;
    __syncthreads();
    for (int o = 128; o > 0; o >>= 1) {
        if (tid < o) r[tid] += r[tid + o];
        __syncthreads();
    }
    if (node < N_NODES) {
        int base = r[0] + sc[tid] - deg;
        rowptr[node] = base;
        int c = base;
#pragma unroll
        for (int s = 0; s < NSUB; ++s) {
            ghist[(size_t)(s * NPART + p) * PSIZE + off] = c;
            c += d[s];
        }
    }
    if (b == NB_SCAN - 1 && tid == 0) rowptr[N_NODES] = N_EDGES;
}

// ---------------- scatter (blocks 0..127) || feature/weight init (blocks 128..) ----------------
#define INIT_ITEMS (800000 + 3 * HD * K2 + N_GRAPHS * HD + N_GRAPHS)
#define INIT_BLOCKS5 ((INIT_ITEMS + 511) / 512)
__global__ __launch_bounds__(512) void k_scatterinit(
    const unsigned* __restrict__ stag, const int* __restrict__ gcount,
    const int* __restrict__ ghist, int* __restrict__ eidx,
    const float* __restrict__ f, unsigned short* __restrict__ c0, unsigned char* __restrict__ f8,
    const float* __restrict__ Ws0, const float* __restrict__ Wn0,
    const float* __restrict__ Ws1, const float* __restrict__ Wn1,
    const float* __restrict__ Ws2, const float* __restrict__ Wn2,
    unsigned short* __restrict__ wt, float* __restrict__ pooled,
    const int* __restrict__ gid, float* __restrict__ counts) {
    if (blockIdx.x < 128) {   // ======== scatter part ========
        __shared__ int cur[PSIZE];
        const int tid = threadIdx.x;
        const int p = blockIdx.x & (NPART - 1);
        const int s = blockIdx.x >> 3;
        const int* gh = ghist + (size_t)blockIdx.x * PSIZE;
        for (int j = tid; j < PSIZE; j += 512) cur[j] = gh[j];
        __syncthreads();
        const int n = gcount[p];
        const int cs = (int)(((long long)s * n) / NSUB);
        const int ce = (int)(((long long)(s + 1) * n) / NSUB);
        const unsigned* sp = stag + (size_t)p * PCAP;
        for (int i = cs + tid; i < ce; i += 512) {
            unsigned v = sp[i];
            int slot = atomicAdd(&cur[v >> 16], 1);
            eidx[slot] = (int)(v & 0xFFFFu);
        }
        return;
    }
    // ======== init part ========
    long long gi = (long long)(blockIdx.x - 128) * 512 + threadIdx.x;
    if (gi < 800000) {   // features: 8 elems/thread -> fp16 h row [m][128] + fp8 row
        int t = (int)gi;
        int row = t >> 4, c8 = (t & 15) * 8;
        const float* p = f + (size_t)row * HD + c8;
        float4 a = *(const float4*)p;
        float4 b = *(const float4*)(p + 4);
        U4H8 v;
        v.h[0] = (_Float16)a.x; v.h[1] = (_Float16)a.y;
        v.h[2] = (_Float16)a.z; v.h[3] = (_Float16)a.w;
        v.h[4] = (_Float16)b.x; v.h[5] = (_Float16)b.y;
        v.h[6] = (_Float16)b.z; v.h[7] = (_Float16)b.w;
        *(uint4*)(c0 + (size_t)row * HD + c8) = v.u;
        int p0 = __builtin_amdgcn_cvt_pk_fp8_f32(a.x, a.y, 0, false);
        p0 = __builtin_amdgcn_cvt_pk_fp8_f32(a.z, a.w, p0, true);
        int p1 = __builtin_amdgcn_cvt_pk_fp8_f32(b.x, b.y, 0, false);
        p1 = __builtin_amdgcn_cvt_pk_fp8_f32(b.z, b.w, p1, true);
        *(uint2*)(f8 + (size_t)row * HD + c8) = make_uint2((unsigned)p0, (unsigned)p1);
        return;
    }
    gi -= 800000;
    if (gi < 3 * HD * K2) {   // weights: transpose+concat -> fp16 [l][n][k]
        int t = (int)gi;
        int l = t / (HD * K2), r = t % (HD * K2);
        int n = r / K2, k = r % K2;
        const float* Ws = (l == 0) ? Ws0 : (l == 1) ? Ws1 : Ws2;
        const float* Wn = (l == 0) ? Wn0 : (l == 1) ? Wn1 : Wn2;
        float w = (k < HD) ? Ws[k * HD + n] : Wn[(k - HD) * HD + n];
        union { unsigned short u; _Float16 h; } c;
        c.h = (_Float16)w;
        wt[t] = c.u;
        return;
    }
    gi -= 3 * HD * K2;
    if (gi < N_GRAPHS * HD) { pooled[gi] = 0.f; return; }
    gi -= (long long)N_GRAPHS * HD;
    if (gi < N_GRAPHS) {   // graph counts via binary search (gid sorted)
        int g = (int)gi;
        int lo = 0, hi = N_NODES;
        while (lo < hi) { int mid = (lo + hi) >> 1; if (gid[mid] < g) lo = mid + 1; else hi = mid; }
        int start = lo;
        lo = 0; hi = N_NODES;
        while (lo < hi) { int mid = (lo + hi) >> 1; if (gid[mid] <= g) lo = mid + 1; else hi = mid; }
        counts[g] = (float)(lo - start);
    }
}

// ---------------- fused gather + SAGE layer ----------------
// 512 thr / 8 waves per 128-node tile. Phase 1: gather neighbor means -> LDS msg (fp16,
// XOR-swizzled). Phase 2: MFMA K=256 where k<128 is h (global_load_lds staged) and
// k>=128 is msg (read straight from LDS; never touches global). Epilogue: write h fp16
// + fp8 shadow, or fused graph-pool for the final layer.
__global__ __launch_bounds__(512) void k_gsage(const unsigned char* __restrict__ h8,   // [m][128] fp8 (gather src)
                                               const unsigned short* __restrict__ hin, // [m][128] fp16 h
                                               const int* __restrict__ rowptr,
                                               const int* __restrict__ eidx,
                                               const unsigned short* __restrict__ wt,  // [n][256] fp16
                                               const float* __restrict__ bias,
                                               unsigned short* __restrict__ hout,      // [m][128] fp16
                                               unsigned char* __restrict__ hout8,      // [m][128] fp8
                                               const int* __restrict__ gid,
                                               float* __restrict__ pooled,
                                               int dopool) {
    __shared__ __align__(16) char arena[65536];
    _Float16* Ah  = (_Float16*)arena;              // [128][64]  16 KB (single-buf, k<128 staged twice)
    _Float16* Bw  = (_Float16*)(arena + 16384);    // [128][64]  16 KB (single-buf)
    _Float16* msg = (_Float16*)(arena + 32768);    // [128][128] 32 KB (gather output)
    float (*gpool)[HD] = (float(*)[HD])arena;      // overlays Ah/Bw after last MFMA (8 KB)
    __shared__ int ginfo[2];
    const int tid = threadIdx.x;
    const int wv = tid >> 6, lane = tid & 63;
    const int m0 = blockIdx.x * 128;
    const int m_off = (wv >> 1) * 32, n_off = (wv & 1) * 64;
    const int l15 = lane & 15, q = lane >> 4;

    auto stageA = [&](int kt) {   // k-tile kt in {0,1}: h half from global
        const int k0 = kt * 64;
#pragma unroll
        for (int i = 0; i < 2; ++i) {
            int idx = tid + i * 512;                 // 1024 16B-chunks
            int row = idx >> 3, c = idx & 7;
            int qs = (c ^ (row & 7)) * 8;            // pre-swizzled source chunk
            int gm = m0 + row;
            if (gm < N_NODES)
                GLOAD_LDS16(hin + (size_t)gm * HD + k0 + qs, &Ah[idx * 8]);
        }
    };
    auto stageB = [&](int kt) {   // k-tile kt in {0..3}
        const int k0 = kt * 64;
#pragma unroll
        for (int i = 0; i < 2; ++i) {
            int idx = tid + i * 512;
            int row = idx >> 3, c = idx & 7;
            int qs = (c ^ (row & 7)) * 8;
            GLOAD_LDS16(wt + (size_t)row * K2 + k0 + qs, &Bw[idx * 8]);
        }
    };

    stageA(0); stageB(0);   // issue now; latency hides under the whole gather phase

    // ---- phase 1: gather 16 nodes per wave into msg LDS ----
    const int epar = lane >> 4;        // 4 edge slots
    const int d0 = l15 * 8;            // 8 fp8 per lane
    for (int i = 0; i < 16; ++i) {
        const int r = wv * 16 + i;
        const int node = m0 + r;
        if (node >= N_NODES) break;
        const int beg = rowptr[node], end = rowptr[node + 1];
        float acc[8] = {0.f, 0.f, 0.f, 0.f, 0.f, 0.f, 0.f, 0.f};
        int j = beg + epar;
        for (; j + 12 < end; j += 16) {    // 16 edges in flight per wave
            int s0 = eidx[j], s1 = eidx[j + 4], s2 = eidx[j + 8], s3 = eidx[j + 12];
            uint2 v0 = *(const uint2*)(h8 + (size_t)s0 * HD + d0);
            uint2 v1 = *(const uint2*)(h8 + (size_t)s1 * HD + d0);
            uint2 v2 = *(const uint2*)(h8 + (size_t)s2 * HD + d0);
            uint2 v3 = *(const uint2*)(h8 + (size_t)s3 * HD + d0);
            f32x2 e;
            e = __builtin_amdgcn_cvt_pk_f32_fp8(v0.x, false); acc[0] += e[0]; acc[1] += e[1];
            e = __builtin_amdgcn_cvt_pk_f32_fp8(v0.x, true);  acc[2] += e[0]; acc[3] += e[1];
            e = __builtin_amdgcn_cvt_pk_f32_fp8(v0.y, false); acc[4] += e[0]; acc[5] += e[1];
            e = __builtin_amdgcn_cvt_pk_f32_fp8(v0.y, true);  acc[6] += e[0]; acc[7] += e[1];
            e = __builtin_amdgcn_cvt_pk_f32_fp8(v1.x, false); acc[0] += e[0]; acc[1] += e[1];
            e = __builtin_amdgcn_cvt_pk_f32_fp8(v1.x, true);  acc[2] += e[0]; acc[3] += e[1];
            e = __builtin_amdgcn_cvt_pk_f32_fp8(v1.y, false); acc[4] += e[0]; acc[5] += e[1];
            e = __builtin_amdgcn_cvt_pk_f32_fp8(v1.y, true);  acc[6] += e[0]; acc[7] += e[1];
            e = __builtin_amdgcn_cvt_pk_f32_fp8(v2.x, false); acc[0] += e[0]; acc[1] += e[1];
            e = __builtin_amdgcn_cvt_pk_f32_fp8(v2.x, true);  acc[2] += e[0]; acc[3] += e[1];
            e = __builtin_amdgcn_cvt_pk_f32_fp8(v2.y, false); acc[4] += e[0]; acc[5] += e[1];
            e = __builtin_amdgcn_cvt_pk_f32_fp8(v2.y, true);  acc[6] += e[0]; acc[7] += e[1];
            e = __builtin_amdgcn_cvt_pk_f32_fp8(v3.x, false); acc[0] += e[0]; acc[1] += e[1];
            e = __builtin_amdgcn_cvt_pk_f32_fp8(v3.x, true);  acc[2] += e[0]; acc[3] += e[1];
            e = __builtin_amdgcn_cvt_pk_f32_fp8(v3.y, false); acc[4] += e[0]; acc[5] += e[1];
            e = __builtin_amdgcn_cvt_pk_f32_fp8(v3.y, true);  acc[6] += e[0]; acc[7] += e[1];
        }
        for (; j < end; j += 4) {
            uint2 v0 = *(const uint2*)(h8 + (size_t)eidx[j] * HD + d0);
            f32x2 e;
            e = __builtin_amdgcn_cvt_pk_f32_fp8(v0.x, false); acc[0] += e[0]; acc[1] += e[1];
            e = __builtin_amdgcn_cvt_pk_f32_fp8(v0.x, true);  acc[2] += e[0]; acc[3] += e[1];
            e = __builtin_amdgcn_cvt_pk_f32_fp8(v0.y, false); acc[4] += e[0]; acc[5] += e[1];
            e = __builtin_amdgcn_cvt_pk_f32_fp8(v0.y, true);  acc[6] += e[0]; acc[7] += e[1];
        }
#pragma unroll
        for (int k = 0; k < 8; ++k) {
            acc[k] += __shfl_xor(acc[k], 16);
            acc[k] += __shfl_xor(acc[k], 32);
        }
        if (epar == 0) {
            float inv = (end > beg) ? 1.0f / (float)(end - beg) : 0.f;
            U4H8 o;
#pragma unroll
            for (int k = 0; k < 8; ++k) o.h[k] = (_Float16)(acc[k] * inv);
            *(uint4*)&msg[(size_t)r * 128 + ((l15 ^ (r & 7)) * 8)] = o.u;
        }
    }
    __syncthreads();   // msg complete + stage(0) drained (vmcnt+lgkm before barrier)

    // ---- phase 2: MFMA over K=256 (kt 0,1 = h from Ah; kt 2,3 = msg from LDS) ----
    f32x4 acc[2][4];
#pragma unroll
    for (int a = 0; a < 2; ++a)
#pragma unroll
        for (int b = 0; b < 4; ++b) acc[a][b] = (f32x4){0.f, 0.f, 0.f, 0.f};

#pragma unroll
    for (int kt = 0; kt < 4; ++kt) {
        f16x8 hf[2][2], wf[4][2];
#pragma unroll
        for (int mt = 0; mt < 2; ++mt) {
            const int row = m_off + mt * 16 + l15;
            const int sw = row & 7;
#pragma unroll
            for (int ks = 0; ks < 2; ++ks) {
                if (kt < 2)
                    hf[mt][ks] = *(const f16x8*)&Ah[row * 64 + (((ks * 4 + q) ^ sw) * 8)];
                else
                    hf[mt][ks] = *(const f16x8*)&msg[row * 128 + ((((kt - 2) * 8 + ks * 4 + q) ^ sw) * 8)];
            }
        }
#pragma unroll
        for (int nt = 0; nt < 4; ++nt) {
            const int row = n_off + nt * 16 + l15;
            const int sw = row & 7;
#pragma unroll
            for (int ks = 0; ks < 2; ++ks)
                wf[nt][ks] = *(const f16x8*)&Bw[row * 64 + (((ks * 4 + q) ^ sw) * 8)];
        }
        __syncthreads();                 // all waves done reading Ah/Bw (lgkm drained)
        if (kt < 3) {
            if (kt == 0) stageA(1);      // overwrite Ah/Bw; loads fly under the MFMAs
            stageB(kt + 1);
        }
#pragma unroll
        for (int mt = 0; mt < 2; ++mt)
#pragma unroll
            for (int nt = 0; nt < 4; ++nt) {
                acc[mt][nt] = __builtin_amdgcn_mfma_f32_16x16x32_f16(wf[nt][0], hf[mt][0], acc[mt][nt], 0, 0, 0);
                acc[mt][nt] = __builtin_amdgcn_mfma_f32_16x16x32_f16(wf[nt][1], hf[mt][1], acc[mt][nt], 0, 0, 0);
            }
        __syncthreads();                 // staged tile landed
    }

    if (!dopool) {
#pragma unroll
        for (int nt = 0; nt < 4; ++nt) {
            int n = n_off + nt * 16 + q * 4;
            float4 bv = *(const float4*)(bias + n);
#pragma unroll
            for (int mt = 0; mt < 2; ++mt) {
                int m = m0 + m_off + mt * 16 + l15;
                if (m < N_NODES) {
                    f32x4 a = acc[mt][nt];
                    float r0 = fmaxf(a[0] + bv.x, 0.f);
                    float r1 = fmaxf(a[1] + bv.y, 0.f);
                    float r2 = fmaxf(a[2] + bv.z, 0.f);
                    float r3 = fmaxf(a[3] + bv.w, 0.f);
                    U2H4 v;
                    v.h[0] = (_Float16)r0; v.h[1] = (_Float16)r1;
                    v.h[2] = (_Float16)r2; v.h[3] = (_Float16)r3;
                    *(uint2*)(hout + (size_t)m * HD + n) = v.u;
                    int p = __builtin_amdgcn_cvt_pk_fp8_f32(r0, r1, 0, false);
                    p = __builtin_amdgcn_cvt_pk_fp8_f32(r2, r3, p, true);
                    *(unsigned int*)(hout8 + (size_t)m * HD + n) = (unsigned)p;
                }
            }
        }
    } else {
        // ---- fused graph mean-pool (gpool overlays Ah/Bw; safe after final barrier) ----
        for (int j = tid; j < NSLOT * HD; j += 512) ((float*)gpool)[j] = 0.f;
        if (tid == 0) {
            ginfo[0] = gid[m0];
            ginfo[1] = gid[min(m0 + 127, N_NODES - 1)];
        }
        __syncthreads();
        const int g_lo = ginfo[0];
        int gg[2];
#pragma unroll
        for (int mt = 0; mt < 2; ++mt) {
            int m = m0 + m_off + mt * 16 + l15;
            gg[mt] = (m < N_NODES) ? gid[m] : -1;
        }
#pragma unroll
        for (int nt = 0; nt < 4; ++nt) {
            int n = n_off + nt * 16 + q * 4;
            float4 bv = *(const float4*)(bias + n);
            int cur = -1;
            float p0 = 0.f, p1 = 0.f, p2 = 0.f, p3 = 0.f;
#pragma unroll
            for (int mt = 0; mt < 2; ++mt) {
                if (gg[mt] < 0) continue;
                f32x4 a = acc[mt][nt];
                float r0 = fmaxf(a[0] + bv.x, 0.f);
                float r1 = fmaxf(a[1] + bv.y, 0.f);
                float r2 = fmaxf(a[2] + bv.z, 0.f);
                float r3 = fmaxf(a[3] + bv.w, 0.f);
                if (gg[mt] != cur) {
                    if (cur >= 0) {
                        int s = cur - g_lo;
                        if (s < NSLOT) {
                            atomicAdd(&gpool[s][n], p0); atomicAdd(&gpool[s][n + 1], p1);
                            atomicAdd(&gpool[s][n + 2], p2); atomicAdd(&gpool[s][n + 3], p3);
                        } else {
                            atomicAdd(&pooled[(size_t)cur * HD + n], p0);
                            atomicAdd(&pooled[(size_t)cur * HD + n + 1], p1);
                            atomicAdd(&pooled[(size_t)cur * HD + n + 2], p2);
                            atomicAdd(&pooled[(size_t)cur * HD + n + 3], p3);
                        }
                    }
                    cur = gg[mt]; p0 = r0; p1 = r1; p2 = r2; p3 = r3;
                } else {
                    p0 += r0; p1 += r1; p2 += r2; p3 += r3;
                }
            }
            if (cur >= 0) {
                int s = cur - g_lo;
                if (s < NSLOT) {
                    atomicAdd(&gpool[s][n], p0); atomicAdd(&gpool[s][n + 1], p1);
                    atomicAdd(&gpool[s][n + 2], p2); atomicAdd(&gpool[s][n + 3], p3);
                } else {
                    atomicAdd(&pooled[(size_t)cur * HD + n], p0);
                    atomicAdd(&pooled[(size_t)cur * HD + n + 1], p1);
                    atomicAdd(&pooled[(size_t)cur * HD + n + 2], p2);
                    atomicAdd(&pooled[(size_t)cur * HD + n + 3], p3);
                }
            }
        }
        __syncthreads();
        const int nslot = min(NSLOT, ginfo[1] - g_lo + 1);
        for (int j = tid; j < nslot * HD; j += 512) {
            float v = gpool[j >> 7][j & 127];
            if (v != 0.f)
                atomicAdd(&pooled[(size_t)(g_lo + (j >> 7)) * HD + (j & 127)], v);
        }
    }
}

// ---------------- classifier (fp32) ----------------
__global__ __launch_bounds__(256) void k_final(const float* __restrict__ pooled,
                                               const float* __restrict__ counts,
                                               const float* __restrict__ Wf,
                                               const float* __restrict__ bf,
                                               float* __restrict__ out) {
    int t = blockIdx.x * 256 + threadIdx.x;
    if (t >= N_GRAPHS * CLS) return;
    int g = t / CLS, c = t % CLS;
    float inv = 1.0f / fmaxf(counts[g], 1.0f);
    float s = 0.f;
    for (int k = 0; k < HD; ++k) s += pooled[(size_t)g * HD + k] * Wf[k * CLS + c];
    out[t] = s * inv + bf[c];
}

extern "C" void kernel_launch(void* const* d_in, const int* in_sizes, int n_in,
                              void* d_out, int out_size, void* d_ws, size_t ws_size,
                              hipStream_t stream) {
    const float* features = (const float*)d_in[0];
    const int*   esrc     = (const int*)d_in[1];
    const int*   edst     = (const int*)d_in[2];
    const int*   gids     = (const int*)d_in[3];
    const float* bs[3]  = {(const float*)d_in[6], (const float*)d_in[9], (const float*)d_in[12]};
    const float* Wf = (const float*)d_in[13];
    const float* bfv = (const float*)d_in[14];
    float* out = (float*)d_out;

    int* gcount = (int*)d_ws;            // 8   \ zeroed together by k_zero (264 ints)
    int* bflag  = gcount + 8;            // 256 /
    int* bsum   = bflag + 256;           // 256 (written before flag release)
    int* rowptr = bsum + 256;            // 50001 (+pad)
    int* eidx   = rowptr + 50008;        // 800000
    unsigned* stag = (unsigned*)(eidx + 800000);
    int* ghist  = (int*)(stag + (size_t)NPART * PCAP);   // 128 planes x 6250
    float* pooled = (float*)(ghist + (size_t)NPART * NSUB * PSIZE);
    float* counts = pooled + N_GRAPHS * HD;
    unsigned short* C0 = (unsigned short*)(counts + 128);    // [N][128] fp16 h x3
    unsigned short* C1 = C0 + (size_t)N_NODES * HD;
    unsigned short* C2 = C1 + (size_t)N_NODES * HD;
    unsigned short* Wt = C2 + (size_t)N_NODES * HD;
    unsigned char* F0 = (unsigned char*)(Wt + 3 * HD * K2);
    unsigned char* F1 = F0 + (size_t)N_NODES * HD;
    unsigned char* F2 = F1 + (size_t)N_NODES * HD;

    k_zero<<<1, 512, 0, stream>>>(gcount);

    k_bin<<<NBIN, 256, 0, stream>>>(esrc, edst, stag, gcount);
    k_hist<<<NPART * NSUB, 512, 0, stream>>>(stag, gcount, ghist);
    k_scan<<<NB_SCAN, 256, 0, stream>>>(ghist, rowptr, bsum, bflag);
    k_scatterinit<<<128 + INIT_BLOCKS5, 512, 0, stream>>>(
        stag, gcount, ghist, eidx,
        features, C0, F0,
        (const float*)d_in[4], (const float*)d_in[5],
        (const float*)d_in[7], (const float*)d_in[8],
        (const float*)d_in[10], (const float*)d_in[11],
        Wt, pooled, gids, counts);

    unsigned short* C[4] = {C0, C1, C2, C0};
    unsigned char* F[4] = {F0, F1, F2, F0};
    for (int l = 0; l < 3; ++l) {
        k_gsage<<<(N_NODES + 127) / 128, 512, 0, stream>>>(
            F[l], C[l], rowptr, eidx, Wt + (size_t)l * HD * K2, bs[l],
            C[l + 1], F[l + 1], gids, pooled, (l == 2) ? 1 : 0);
    }

    k_final<<<(N_GRAPHS * CLS + 255) / 256, 256, 0, stream>>>(pooled, counts, Wf, bfv, out);
}

// Round 7
// 301.477 us; speedup vs baseline: 1.1720x; 1.1720x over previous
//
#include <hip/hip_runtime.h>

#define N_NODES  50000
#define N_EDGES  800000
#define N_GRAPHS 128
#define HD       128
#define K2       256
#define CLS      10
#define NPART    8
#define PSIZE    (N_NODES / NPART)          // 6250
#define NSUB     16
#define NB_SCAN  ((N_NODES + 255) / 256)    // 196
#define NBIN     1600
#define CHUNK    (N_EDGES / NBIN)           // 500
#define PCAP     131072
#define NSLOT    16

typedef __attribute__((ext_vector_type(8))) _Float16 f16x8;
typedef __attribute__((ext_vector_type(4))) float f32x4;
typedef __attribute__((ext_vector_type(2))) float f32x2;

union U4H8 { uint4 u; _Float16 h[8]; };
union U2H4 { uint2 u; _Float16 h[4]; };

typedef const __attribute__((address_space(1))) void* gptr_t;
typedef __attribute__((address_space(3))) void* lptr_t;
#define GLOAD_LDS16(g, l) \
    __builtin_amdgcn_global_load_lds((gptr_t)(g), (lptr_t)(l), 16, 0, 0)

// ---------------- zero gcount(8) + bflag(256), adjacent ----------------
__global__ __launch_bounds__(512) void k_zero(int* __restrict__ z) {
    int i = threadIdx.x;
    if (i < 264) z[i] = 0;
}

// ---------------- bin edges by dst partition (LDS histogram + packed staging) ----------------
__global__ __launch_bounds__(256) void k_bin(const int* __restrict__ src, const int* __restrict__ dst,
                                             unsigned* __restrict__ stag, int* __restrict__ gcount) {
    __shared__ int lcount[NPART];
    __shared__ int lbase[NPART];
    const int tid = threadIdx.x;
    const int lo = blockIdx.x * CHUNK;
    if (tid < NPART) lcount[tid] = 0;
    __syncthreads();
    int dc[2], sc[2];
#pragma unroll
    for (int it = 0; it < 2; ++it) {
        int i = lo + tid + it * 256;
        dc[it] = -1;
        if (i < lo + CHUNK) {
            int d = dst[i];
            dc[it] = d; sc[it] = src[i];
            atomicAdd(&lcount[d / PSIZE], 1);
        }
    }
    __syncthreads();
    if (tid < NPART) {
        lbase[tid] = atomicAdd(&gcount[tid], lcount[tid]);
        lcount[tid] = 0;   // reuse as cursor
    }
    __syncthreads();
#pragma unroll
    for (int it = 0; it < 2; ++it) {
        if (dc[it] >= 0) {
            int p = dc[it] / PSIZE;
            int slot = atomicAdd(&lcount[p], 1);
            stag[(size_t)p * PCAP + lbase[p] + slot] =
                (unsigned)sc[it] | ((unsigned)(dc[it] - p * PSIZE) << 16);
        }
    }
}

// ---------------- hist: per-(partition, 1/16-edge-chunk) LDS histogram -> global plane ----------------
__global__ __launch_bounds__(512) void k_hist(const unsigned* __restrict__ stag,
                                              const int* __restrict__ gcount,
                                              int* __restrict__ ghist) {
    __shared__ int hist[PSIZE];
    const int tid = threadIdx.x;
    const int p = blockIdx.x & (NPART - 1);
    const int s = blockIdx.x >> 3;
    for (int j = tid; j < PSIZE; j += 512) hist[j] = 0;
    __syncthreads();
    const int n = gcount[p];
    const int cs = (int)(((long long)s * n) / NSUB);
    const int ce = (int)(((long long)(s + 1) * n) / NSUB);
    const unsigned* sp = stag + (size_t)p * PCAP;
    for (int i = cs + tid; i < ce; i += 512)
        atomicAdd(&hist[sp[i] >> 16], 1);
    __syncthreads();
    int* gh = ghist + (size_t)blockIdx.x * PSIZE;
    for (int j = tid; j < PSIZE; j += 512) gh[j] = hist[j];
}

// ---------------- scan: deg = sum of 16 planes; rowptr via decoupled lookback; planes -> cursors ----------------
__global__ __launch_bounds__(256) void k_scan(int* __restrict__ ghist,
                                              int* __restrict__ rowptr,
                                              int* __restrict__ bsum, int* __restrict__ bflag) {
    __shared__ int sc[256];
    __shared__ int r[256];
    const int tid = threadIdx.x;
    const int b = blockIdx.x;
    const int node = b * 256 + tid;
    int d[NSUB];
    int deg = 0, p = 0, off = 0;
    if (node < N_NODES) {
        p = node / PSIZE; off = node - p * PSIZE;
#pragma unroll
        for (int s = 0; s < NSUB; ++s) {
            d[s] = ghist[(size_t)(s * NPART + p) * PSIZE + off];
            deg += d[s];
        }
    }
    sc[tid] = deg;
    __syncthreads();
    for (int o = 1; o < 256; o <<= 1) {
        int add = (tid >= o) ? sc[tid - o] : 0;
        __syncthreads();
        sc[tid] += add;
        __syncthreads();
    }
    if (tid == 255) {
        __hip_atomic_store(&bsum[b], sc[255], __ATOMIC_RELAXED, __HIP_MEMORY_SCOPE_AGENT);
        __hip_atomic_store(&bflag[b], 1, __ATOMIC_RELEASE, __HIP_MEMORY_SCOPE_AGENT);
    }
    int agg = 0;
    if (tid < b) {
        while (__hip_atomic_load(&bflag[tid], __ATOMIC_ACQUIRE, __HIP_MEMORY_SCOPE_AGENT) == 0) {}
        agg = __hip_atomic_load(&bsum[tid], __ATOMIC_RELAXED, __HIP_MEMORY_SCOPE_AGENT);
    }
    r[tid] = agg;
    __syncthreads();
    for (int o = 128; o > 0; o >>= 1) {
        if (tid < o) r[tid] += r[tid + o];
        __syncthreads();
    }
    if (node < N_NODES) {
        int base = r[0] + sc[tid] - deg;
        rowptr[node] = base;
        int c = base;
#pragma unroll
        for (int s = 0; s < NSUB; ++s) {
            ghist[(size_t)(s * NPART + p) * PSIZE + off] = c;
            c += d[s];
        }
    }
    if (b == NB_SCAN - 1 && tid == 0) rowptr[N_NODES] = N_EDGES;
}

// ---------------- scatter (blocks 0..127) || feature/weight init (blocks 128..) ----------------
#define INIT_ITEMS (800000 + 3 * HD * K2 + N_GRAPHS * HD + N_GRAPHS)
#define INIT_BLOCKS5 ((INIT_ITEMS + 511) / 512)
__global__ __launch_bounds__(512) void k_scatterinit(
    const unsigned* __restrict__ stag, const int* __restrict__ gcount,
    const int* __restrict__ ghist, int* __restrict__ eidx,
    const float* __restrict__ f, unsigned short* __restrict__ c0, unsigned char* __restrict__ f8,
    const float* __restrict__ Ws0, const float* __restrict__ Wn0,
    const float* __restrict__ Ws1, const float* __restrict__ Wn1,
    const float* __restrict__ Ws2, const float* __restrict__ Wn2,
    unsigned short* __restrict__ wt, float* __restrict__ pooled,
    const int* __restrict__ gid, float* __restrict__ counts) {
    if (blockIdx.x < 128) {   // ======== scatter part ========
        __shared__ int cur[PSIZE];
        const int tid = threadIdx.x;
        const int p = blockIdx.x & (NPART - 1);
        const int s = blockIdx.x >> 3;
        const int* gh = ghist + (size_t)blockIdx.x * PSIZE;
        for (int j = tid; j < PSIZE; j += 512) cur[j] = gh[j];
        __syncthreads();
        const int n = gcount[p];
        const int cs = (int)(((long long)s * n) / NSUB);
        const int ce = (int)(((long long)(s + 1) * n) / NSUB);
        const unsigned* sp = stag + (size_t)p * PCAP;
        for (int i = cs + tid; i < ce; i += 512) {
            unsigned v = sp[i];
            int slot = atomicAdd(&cur[v >> 16], 1);
            eidx[slot] = (int)(v & 0xFFFFu);
        }
        return;
    }
    // ======== init part ========
    long long gi = (long long)(blockIdx.x - 128) * 512 + threadIdx.x;
    if (gi < 800000) {   // features: 8 elems/thread -> fp16 (K2-strided h-part) + fp8 row
        int t = (int)gi;
        int row = t >> 4, c8 = (t & 15) * 8;
        const float* p = f + (size_t)row * HD + c8;
        float4 a = *(const float4*)p;
        float4 b = *(const float4*)(p + 4);
        U4H8 v;
        v.h[0] = (_Float16)a.x; v.h[1] = (_Float16)a.y;
        v.h[2] = (_Float16)a.z; v.h[3] = (_Float16)a.w;
        v.h[4] = (_Float16)b.x; v.h[5] = (_Float16)b.y;
        v.h[6] = (_Float16)b.z; v.h[7] = (_Float16)b.w;
        *(uint4*)(c0 + (size_t)row * K2 + c8) = v.u;
        int p0 = __builtin_amdgcn_cvt_pk_fp8_f32(a.x, a.y, 0, false);
        p0 = __builtin_amdgcn_cvt_pk_fp8_f32(a.z, a.w, p0, true);
        int p1 = __builtin_amdgcn_cvt_pk_fp8_f32(b.x, b.y, 0, false);
        p1 = __builtin_amdgcn_cvt_pk_fp8_f32(b.z, b.w, p1, true);
        *(uint2*)(f8 + (size_t)row * HD + c8) = make_uint2((unsigned)p0, (unsigned)p1);
        return;
    }
    gi -= 800000;
    if (gi < 3 * HD * K2) {   // weights: transpose+concat -> fp16 [l][n][k]
        int t = (int)gi;
        int l = t / (HD * K2), r = t % (HD * K2);
        int n = r / K2, k = r % K2;
        const float* Ws = (l == 0) ? Ws0 : (l == 1) ? Ws1 : Ws2;
        const float* Wn = (l == 0) ? Wn0 : (l == 1) ? Wn1 : Wn2;
        float w = (k < HD) ? Ws[k * HD + n] : Wn[(k - HD) * HD + n];
        union { unsigned short u; _Float16 h; } c;
        c.h = (_Float16)w;
        wt[t] = c.u;
        return;
    }
    gi -= 3 * HD * K2;
    if (gi < N_GRAPHS * HD) { pooled[gi] = 0.f; return; }
    gi -= (long long)N_GRAPHS * HD;
    if (gi < N_GRAPHS) {   // graph counts via binary search (gid sorted)
        int g = (int)gi;
        int lo = 0, hi = N_NODES;
        while (lo < hi) { int mid = (lo + hi) >> 1; if (gid[mid] < g) lo = mid + 1; else hi = mid; }
        int start = lo;
        lo = 0; hi = N_NODES;
        while (lo < hi) { int mid = (lo + hi) >> 1; if (gid[mid] <= g) lo = mid + 1; else hi = mid; }
        counts[g] = (float)(lo - start);
    }
}

// ---------------- gather: one wave per node, 16B/lane fp8 loads, 8 edge slots, 16 in flight ----------------
__global__ __launch_bounds__(256) void k_gather(const unsigned char* __restrict__ h8,
                                                const int* __restrict__ rowptr,
                                                const int* __restrict__ eidx,
                                                unsigned short* __restrict__ msg) {
    const int node = (blockIdx.x * 256 + threadIdx.x) >> 6;
    const int lane = threadIdx.x & 63;
    if (node >= N_NODES) return;
    const int slot = lane >> 3;        // 8 edge slots
    const int d0 = (lane & 7) * 16;    // 16 fp8 per lane = 16 B
    const int beg = rowptr[node], end = rowptr[node + 1];
    float acc[16];
#pragma unroll
    for (int i = 0; i < 16; ++i) acc[i] = 0.f;
#define ACC16(v)                                                                        \
    do {                                                                                \
        f32x2 e;                                                                        \
        e = __builtin_amdgcn_cvt_pk_f32_fp8((v).x, false); acc[0] += e[0]; acc[1] += e[1];  \
        e = __builtin_amdgcn_cvt_pk_f32_fp8((v).x, true);  acc[2] += e[0]; acc[3] += e[1];  \
        e = __builtin_amdgcn_cvt_pk_f32_fp8((v).y, false); acc[4] += e[0]; acc[5] += e[1];  \
        e = __builtin_amdgcn_cvt_pk_f32_fp8((v).y, true);  acc[6] += e[0]; acc[7] += e[1];  \
        e = __builtin_amdgcn_cvt_pk_f32_fp8((v).z, false); acc[8] += e[0]; acc[9] += e[1];  \
        e = __builtin_amdgcn_cvt_pk_f32_fp8((v).z, true);  acc[10] += e[0]; acc[11] += e[1];\
        e = __builtin_amdgcn_cvt_pk_f32_fp8((v).w, false); acc[12] += e[0]; acc[13] += e[1];\
        e = __builtin_amdgcn_cvt_pk_f32_fp8((v).w, true);  acc[14] += e[0]; acc[15] += e[1];\
    } while (0)
    int j = beg + slot;
    for (; j + 8 < end; j += 16) {     // 2 loads/lane x 8 slots = 16 edges in flight
        int s0 = eidx[j], s1 = eidx[j + 8];
        uint4 v0 = *(const uint4*)(h8 + (size_t)s0 * HD + d0);
        uint4 v1 = *(const uint4*)(h8 + (size_t)s1 * HD + d0);
        ACC16(v0);
        ACC16(v1);
    }
    for (; j < end; j += 8) {
        uint4 v0 = *(const uint4*)(h8 + (size_t)eidx[j] * HD + d0);
        ACC16(v0);
    }
#undef ACC16
#pragma unroll
    for (int i = 0; i < 16; ++i) {
        acc[i] += __shfl_xor(acc[i], 8);
        acc[i] += __shfl_xor(acc[i], 16);
        acc[i] += __shfl_xor(acc[i], 32);
    }
    if (slot == 0) {
        float inv = (end > beg) ? 1.0f / (float)(end - beg) : 0.f;
        U4H8 o0, o1;
#pragma unroll
        for (int i = 0; i < 8; ++i) {
            o0.h[i] = (_Float16)(acc[i] * inv);
            o1.h[i] = (_Float16)(acc[8 + i] * inv);
        }
        unsigned short* dst = msg + (size_t)node * K2 + HD + (lane & 7) * 16;
        *(uint4*)dst = o0.u;
        *(uint4*)(dst + 8) = o1.u;
    }
}

// ---------------- SAGE layer: MFMA K=256; epilogue = write h/fp8 OR fused graph-pool ----------------
__global__ __launch_bounds__(256) void k_sage(const unsigned short* __restrict__ hin,  // [m][256] fp16
                                              const unsigned short* __restrict__ wt,   // [n][256] fp16
                                              const float* __restrict__ bias,
                                              unsigned short* __restrict__ hout,       // [m][256] h-part
                                              unsigned char* __restrict__ hout8,       // [m][128] fp8
                                              const int* __restrict__ gid,
                                              float* __restrict__ pooled,
                                              int write16, int dopool) {
    __shared__ __align__(16) _Float16 Ah[2][128 * 64];
    __shared__ __align__(16) _Float16 Bw[2][128 * 64];
    __shared__ float gpool[NSLOT][HD];
    __shared__ int ginfo[2];
    const int tid = threadIdx.x;
    const int wv = tid >> 6, lane = tid & 63;
    const int m0 = blockIdx.x * 128;
    const int m_off = (wv >> 1) * 64, n_off = (wv & 1) * 64;
    const int l15 = lane & 15, q = lane >> 4;

    f32x4 acc[4][4];
#pragma unroll
    for (int a = 0; a < 4; ++a)
#pragma unroll
        for (int b = 0; b < 4; ++b) acc[a][b] = (f32x4){0.f, 0.f, 0.f, 0.f};

    auto stage = [&](int bsel, int kt) {
        const int k0 = kt * 64;
#pragma unroll
        for (int i = 0; i < 4; ++i) {
            int idx = tid + i * 256;             // 1024 16B-chunks per operand tile
            int row = idx >> 3, c = idx & 7;
            int qs = (c ^ (row & 7)) * 8;        // pre-swizzled source chunk (halfs)
            int gm = m0 + row;
            if (gm < N_NODES)
                GLOAD_LDS16(hin + (size_t)gm * K2 + k0 + qs, &Ah[bsel][idx * 8]);
            GLOAD_LDS16(wt + (size_t)row * K2 + k0 + qs, &Bw[bsel][idx * 8]);
        }
    };

    stage(0, 0);
    __syncthreads();   // drains vmcnt(0): buf0 ready
#pragma unroll
    for (int kt = 0; kt < 4; ++kt) {
        const int b = kt & 1;
        if (kt < 3) stage(b ^ 1, kt + 1);        // prefetch next tile into other buffer
        f16x8 hf[4][2], wf[4][2];
#pragma unroll
        for (int mt = 0; mt < 4; ++mt) {
            const int row = m_off + mt * 16 + l15;
            const int sw = row & 7;
#pragma unroll
            for (int ks = 0; ks < 2; ++ks)
                hf[mt][ks] = *(const f16x8*)&Ah[b][row * 64 + (((ks * 4 + q) ^ sw) * 8)];
        }
#pragma unroll
        for (int nt = 0; nt < 4; ++nt) {
            const int row = n_off + nt * 16 + l15;
            const int sw = row & 7;
#pragma unroll
            for (int ks = 0; ks < 2; ++ks)
                wf[nt][ks] = *(const f16x8*)&Bw[b][row * 64 + (((ks * 4 + q) ^ sw) * 8)];
        }
#pragma unroll
        for (int mt = 0; mt < 4; ++mt)
#pragma unroll
            for (int nt = 0; nt < 4; ++nt) {
                acc[mt][nt] = __builtin_amdgcn_mfma_f32_16x16x32_f16(wf[nt][0], hf[mt][0], acc[mt][nt], 0, 0, 0);
                acc[mt][nt] = __builtin_amdgcn_mfma_f32_16x16x32_f16(wf[nt][1], hf[mt][1], acc[mt][nt], 0, 0, 0);
            }
        __syncthreads();
    }
    if (!dopool) {
#pragma unroll
        for (int nt = 0; nt < 4; ++nt) {
            int n = n_off + nt * 16 + q * 4;
            float4 bv = *(const float4*)(bias + n);
#pragma unroll
            for (int mt = 0; mt < 4; ++mt) {
                int m = m0 + m_off + mt * 16 + l15;
                if (m < N_NODES) {
                    f32x4 a = acc[mt][nt];
                    float r0 = fmaxf(a[0] + bv.x, 0.f);
                    float r1 = fmaxf(a[1] + bv.y, 0.f);
                    float r2 = fmaxf(a[2] + bv.z, 0.f);
                    float r3 = fmaxf(a[3] + bv.w, 0.f);
                    if (write16) {
                        U2H4 v;
                        v.h[0] = (_Float16)r0; v.h[1] = (_Float16)r1;
                        v.h[2] = (_Float16)r2; v.h[3] = (_Float16)r3;
                        *(uint2*)(hout + (size_t)m * K2 + n) = v.u;
                    }
                    int p = __builtin_amdgcn_cvt_pk_fp8_f32(r0, r1, 0, false);
                    p = __builtin_amdgcn_cvt_pk_fp8_f32(r2, r3, p, true);
                    *(unsigned int*)(hout8 + (size_t)m * HD + n) = (unsigned)p;
                }
            }
        }
    } else {
        // ---- fused graph mean-pool: LDS per-graph partials, then sparse flush ----
        for (int j = tid; j < NSLOT * HD; j += 256) ((float*)gpool)[j] = 0.f;
        if (tid == 0) {
            ginfo[0] = gid[m0];
            ginfo[1] = gid[min(m0 + 127, N_NODES - 1)];
        }
        __syncthreads();
        const int g_lo = ginfo[0];
        int gg[4];
#pragma unroll
        for (int mt = 0; mt < 4; ++mt) {
            int m = m0 + m_off + mt * 16 + l15;
            gg[mt] = (m < N_NODES) ? gid[m] : -1;
        }
#pragma unroll
        for (int nt = 0; nt < 4; ++nt) {
            int n = n_off + nt * 16 + q * 4;
            float4 bv = *(const float4*)(bias + n);
            int cur = -1;
            float p0 = 0.f, p1 = 0.f, p2 = 0.f, p3 = 0.f;
#pragma unroll
            for (int mt = 0; mt < 4; ++mt) {
                if (gg[mt] < 0) continue;
                f32x4 a = acc[mt][nt];
                float r0 = fmaxf(a[0] + bv.x, 0.f);
                float r1 = fmaxf(a[1] + bv.y, 0.f);
                float r2 = fmaxf(a[2] + bv.z, 0.f);
                float r3 = fmaxf(a[3] + bv.w, 0.f);
                if (gg[mt] != cur) {
                    if (cur >= 0) {
                        int s = cur - g_lo;
                        if (s < NSLOT) {
                            atomicAdd(&gpool[s][n], p0); atomicAdd(&gpool[s][n + 1], p1);
                            atomicAdd(&gpool[s][n + 2], p2); atomicAdd(&gpool[s][n + 3], p3);
                        } else {
                            atomicAdd(&pooled[(size_t)cur * HD + n], p0);
                            atomicAdd(&pooled[(size_t)cur * HD + n + 1], p1);
                            atomicAdd(&pooled[(size_t)cur * HD + n + 2], p2);
                            atomicAdd(&pooled[(size_t)cur * HD + n + 3], p3);
                        }
                    }
                    cur = gg[mt]; p0 = r0; p1 = r1; p2 = r2; p3 = r3;
                } else {
                    p0 += r0; p1 += r1; p2 += r2; p3 += r3;
                }
            }
            if (cur >= 0) {
                int s = cur - g_lo;
                if (s < NSLOT) {
                    atomicAdd(&gpool[s][n], p0); atomicAdd(&gpool[s][n + 1], p1);
                    atomicAdd(&gpool[s][n + 2], p2); atomicAdd(&gpool[s][n + 3], p3);
                } else {
                    atomicAdd(&pooled[(size_t)cur * HD + n], p0);
                    atomicAdd(&pooled[(size_t)cur * HD + n + 1], p1);
                    atomicAdd(&pooled[(size_t)cur * HD + n + 2], p2);
                    atomicAdd(&pooled[(size_t)cur * HD + n + 3], p3);
                }
            }
        }
        __syncthreads();
        const int nslot = min(NSLOT, ginfo[1] - g_lo + 1);
        for (int j = tid; j < nslot * HD; j += 256) {
            float v = gpool[j >> 7][j & 127];
            if (v != 0.f)
                atomicAdd(&pooled[(size_t)(g_lo + (j >> 7)) * HD + (j & 127)], v);
        }
    }
}

// ---------------- classifier (fp32) ----------------
__global__ __launch_bounds__(256) void k_final(const float* __restrict__ pooled,
                                               const float* __restrict__ counts,
                                               const float* __restrict__ Wf,
                                               const float* __restrict__ bf,
                                               float* __restrict__ out) {
    int t = blockIdx.x * 256 + threadIdx.x;
    if (t >= N_GRAPHS * CLS) return;
    int g = t / CLS, c = t % CLS;
    float inv = 1.0f / fmaxf(counts[g], 1.0f);
    float s = 0.f;
    for (int k = 0; k < HD; ++k) s += pooled[(size_t)g * HD + k] * Wf[k * CLS + c];
    out[t] = s * inv + bf[c];
}

extern "C" void kernel_launch(void* const* d_in, const int* in_sizes, int n_in,
                              void* d_out, int out_size, void* d_ws, size_t ws_size,
                              hipStream_t stream) {
    const float* features = (const float*)d_in[0];
    const int*   esrc     = (const int*)d_in[1];
    const int*   edst     = (const int*)d_in[2];
    const int*   gids     = (const int*)d_in[3];
    const float* bs[3]  = {(const float*)d_in[6], (const float*)d_in[9], (const float*)d_in[12]};
    const float* Wf = (const float*)d_in[13];
    const float* bfv = (const float*)d_in[14];
    float* out = (float*)d_out;

    int* gcount = (int*)d_ws;            // 8   \ zeroed together by k_zero (264 ints)
    int* bflag  = gcount + 8;            // 256 /
    int* bsum   = bflag + 256;           // 256 (written before flag release)
    int* rowptr = bsum + 256;            // 50001 (+pad)
    int* eidx   = rowptr + 50008;        // 800000
    unsigned* stag = (unsigned*)(eidx + 800000);
    int* ghist  = (int*)(stag + (size_t)NPART * PCAP);   // 128 planes x 6250
    float* pooled = (float*)(ghist + (size_t)NPART * NSUB * PSIZE);
    float* counts = pooled + N_GRAPHS * HD;
    unsigned short* C0 = (unsigned short*)(counts + 128);    // 50000*256 fp16 x3 (h|msg)
    unsigned short* C1 = C0 + (size_t)N_NODES * K2;
    unsigned short* C2 = C1 + (size_t)N_NODES * K2;
    unsigned short* Wt = C2 + (size_t)N_NODES * K2;
    unsigned char* F0 = (unsigned char*)(Wt + 3 * HD * K2);
    unsigned char* F1 = F0 + (size_t)N_NODES * HD;
    unsigned char* F2 = F1 + (size_t)N_NODES * HD;

    k_zero<<<1, 512, 0, stream>>>(gcount);

    k_bin<<<NBIN, 256, 0, stream>>>(esrc, edst, stag, gcount);
    k_hist<<<NPART * NSUB, 512, 0, stream>>>(stag, gcount, ghist);
    k_scan<<<NB_SCAN, 256, 0, stream>>>(ghist, rowptr, bsum, bflag);
    k_scatterinit<<<128 + INIT_BLOCKS5, 512, 0, stream>>>(
        stag, gcount, ghist, eidx,
        features, C0, F0,
        (const float*)d_in[4], (const float*)d_in[5],
        (const float*)d_in[7], (const float*)d_in[8],
        (const float*)d_in[10], (const float*)d_in[11],
        Wt, pooled, gids, counts);

    unsigned short* C[4] = {C0, C1, C2, C0};
    unsigned char* F[4] = {F0, F1, F2, F0};
    for (int l = 0; l < 3; ++l) {
        k_gather<<<(N_NODES * 64 + 255) / 256, 256, 0, stream>>>(F[l], rowptr, eidx, C[l]);
        k_sage<<<(N_NODES + 127) / 128, 256, 0, stream>>>(
            C[l], Wt + (size_t)l * HD * K2, bs[l], C[l + 1], F[l + 1],
            gids, pooled, (l < 2) ? 1 : 0, (l == 2) ? 1 : 0);
    }

    k_final<<<(N_GRAPHS * CLS + 255) / 256, 256, 0, stream>>>(pooled, counts, Wf, bfv, out);
}

// Round 9
// 290.808 us; speedup vs baseline: 1.2150x; 1.0367x over previous
//
#include <hip/hip_runtime.h>

#define N_NODES  50000
#define N_EDGES  800000
#define N_GRAPHS 128
#define HD       128
#define K2       256
#define CLS      10
#define NPART    8
#define PSIZE    (N_NODES / NPART)          // 6250
#define NSUB     16
#define NB_SCAN  ((N_NODES + 255) / 256)    // 196
#define NBIN     1600
#define CHUNK    (N_EDGES / NBIN)           // 500
#define PCAP     131072
#define NSLOT    16

typedef __attribute__((ext_vector_type(8))) _Float16 f16x8;
typedef __attribute__((ext_vector_type(4))) float f32x4;
typedef __attribute__((ext_vector_type(2))) float f32x2;

union U4H8 { uint4 u; _Float16 h[8]; };
union U2H4 { uint2 u; _Float16 h[4]; };

typedef const __attribute__((address_space(1))) void* gptr_t;
typedef __attribute__((address_space(3))) void* lptr_t;
#define GLOAD_LDS16(g, l) \
    __builtin_amdgcn_global_load_lds((gptr_t)(g), (lptr_t)(l), 16, 0, 0)

// ---------------- zero gcount(8) + bflag(256), adjacent ----------------
__global__ __launch_bounds__(512) void k_zero(int* __restrict__ z) {
    int i = threadIdx.x;
    if (i < 264) z[i] = 0;
}

// ---------------- bin edges by dst partition (LDS histogram + packed staging) ----------------
__global__ __launch_bounds__(256) void k_bin(const int* __restrict__ src, const int* __restrict__ dst,
                                             unsigned* __restrict__ stag, int* __restrict__ gcount) {
    __shared__ int lcount[NPART];
    __shared__ int lbase[NPART];
    const int tid = threadIdx.x;
    const int lo = blockIdx.x * CHUNK;
    if (tid < NPART) lcount[tid] = 0;
    __syncthreads();
    int dc[2], sc[2];
#pragma unroll
    for (int it = 0; it < 2; ++it) {
        int i = lo + tid + it * 256;
        dc[it] = -1;
        if (i < lo + CHUNK) {
            int d = dst[i];
            dc[it] = d; sc[it] = src[i];
            atomicAdd(&lcount[d / PSIZE], 1);
        }
    }
    __syncthreads();
    if (tid < NPART) {
        lbase[tid] = atomicAdd(&gcount[tid], lcount[tid]);
        lcount[tid] = 0;   // reuse as cursor
    }
    __syncthreads();
#pragma unroll
    for (int it = 0; it < 2; ++it) {
        if (dc[it] >= 0) {
            int p = dc[it] / PSIZE;
            int slot = atomicAdd(&lcount[p], 1);
            stag[(size_t)p * PCAP + lbase[p] + slot] =
                (unsigned)sc[it] | ((unsigned)(dc[it] - p * PSIZE) << 16);
        }
    }
}

// ---------------- hist: per-(partition, 1/16-edge-chunk) LDS histogram -> global plane ----------------
__global__ __launch_bounds__(512) void k_hist(const unsigned* __restrict__ stag,
                                              const int* __restrict__ gcount,
                                              int* __restrict__ ghist) {
    __shared__ int hist[PSIZE];
    const int tid = threadIdx.x;
    const int p = blockIdx.x & (NPART - 1);
    const int s = blockIdx.x >> 3;
    for (int j = tid; j < PSIZE; j += 512) hist[j] = 0;
    __syncthreads();
    const int n = gcount[p];
    const int cs = (int)(((long long)s * n) / NSUB);
    const int ce = (int)(((long long)(s + 1) * n) / NSUB);
    const unsigned* sp = stag + (size_t)p * PCAP;
    for (int i = cs + tid; i < ce; i += 512)
        atomicAdd(&hist[sp[i] >> 16], 1);
    __syncthreads();
    int* gh = ghist + (size_t)blockIdx.x * PSIZE;
    for (int j = tid; j < PSIZE; j += 512) gh[j] = hist[j];
}

// ---------------- scan: deg = sum of 16 planes; rowptr via decoupled lookback; planes -> cursors ----------------
__global__ __launch_bounds__(256) void k_scan(int* __restrict__ ghist,
                                              int* __restrict__ rowptr,
                                              int* __restrict__ bsum, int* __restrict__ bflag) {
    __shared__ int sc[256];
    __shared__ int r[256];
    const int tid = threadIdx.x;
    const int b = blockIdx.x;
    const int node = b * 256 + tid;
    int d[NSUB];
    int deg = 0, p = 0, off = 0;
    if (node < N_NODES) {
        p = node / PSIZE; off = node - p * PSIZE;
#pragma unroll
        for (int s = 0; s < NSUB; ++s) {
            d[s] = ghist[(size_t)(s * NPART + p) * PSIZE + off];
            deg += d[s];
        }
    }
    sc[tid] = deg;
    __syncthreads();
    for (int o = 1; o < 256; o <<= 1) {
        int add = (tid >= o) ? sc[tid - o] : 0;
        __syncthreads();
        sc[tid] += add;
        __syncthreads();
    }
    if (tid == 255) {
        __hip_atomic_store(&bsum[b], sc[255], __ATOMIC_RELAXED, __HIP_MEMORY_SCOPE_AGENT);
        __hip_atomic_store(&bflag[b], 1, __ATOMIC_RELEASE, __HIP_MEMORY_SCOPE_AGENT);
    }
    int agg = 0;
    if (tid < b) {
        while (__hip_atomic_load(&bflag[tid], __ATOMIC_ACQUIRE, __HIP_MEMORY_SCOPE_AGENT) == 0) {}
        agg = __hip_atomic_load(&bsum[tid], __ATOMIC_RELAXED, __HIP_MEMORY_SCOPE_AGENT);
    }
    r[tid] = agg;
    __syncthreads();
    for (int o = 128; o > 0; o >>= 1) {
        if (tid < o) r[tid] += r[tid + o];
        __syncthreads();
    }
    if (node < N_NODES) {
        int base = r[0] + sc[tid] - deg;
        rowptr[node] = base;
        int c = base;
#pragma unroll
        for (int s = 0; s < NSUB; ++s) {
            ghist[(size_t)(s * NPART + p) * PSIZE + off] = c;
            c += d[s];
        }
    }
    if (b == NB_SCAN - 1 && tid == 0) rowptr[N_NODES] = N_EDGES;
}

// ---------------- scatter (blocks 0..127) || feature/weight init (blocks 128..) ----------------
#define INIT_ITEMS (800000 + 3 * HD * K2 + N_GRAPHS * HD + N_GRAPHS)
#define INIT_BLOCKS5 ((INIT_ITEMS + 511) / 512)
__global__ __launch_bounds__(512) void k_scatterinit(
    const unsigned* __restrict__ stag, const int* __restrict__ gcount,
    const int* __restrict__ ghist, int* __restrict__ eidx,
    const float* __restrict__ f, unsigned short* __restrict__ c0, unsigned char* __restrict__ f8,
    const float* __restrict__ Ws0, const float* __restrict__ Wn0,
    const float* __restrict__ Ws1, const float* __restrict__ Wn1,
    const float* __restrict__ Ws2, const float* __restrict__ Wn2,
    unsigned short* __restrict__ wt, float* __restrict__ pooled,
    const int* __restrict__ gid, float* __restrict__ counts) {
    if (blockIdx.x < 128) {   // ======== scatter part ========
        __shared__ int cur[PSIZE];
        const int tid = threadIdx.x;
        const int p = blockIdx.x & (NPART - 1);
        const int s = blockIdx.x >> 3;
        const int* gh = ghist + (size_t)blockIdx.x * PSIZE;
        for (int j = tid; j < PSIZE; j += 512) cur[j] = gh[j];
        __syncthreads();
        const int n = gcount[p];
        const int cs = (int)(((long long)s * n) / NSUB);
        const int ce = (int)(((long long)(s + 1) * n) / NSUB);
        const unsigned* sp = stag + (size_t)p * PCAP;
        for (int i = cs + tid; i < ce; i += 512) {
            unsigned v = sp[i];
            int slot = atomicAdd(&cur[v >> 16], 1);
            eidx[slot] = (int)(v & 0xFFFFu);
        }
        return;
    }
    // ======== init part ========
    long long gi = (long long)(blockIdx.x - 128) * 512 + threadIdx.x;
    if (gi < 800000) {   // features: 8 elems/thread -> fp16 (K2-strided h-part) + fp8 row
        int t = (int)gi;
        int row = t >> 4, c8 = (t & 15) * 8;
        const float* p = f + (size_t)row * HD + c8;
        float4 a = *(const float4*)p;
        float4 b = *(const float4*)(p + 4);
        U4H8 v;
        v.h[0] = (_Float16)a.x; v.h[1] = (_Float16)a.y;
        v.h[2] = (_Float16)a.z; v.h[3] = (_Float16)a.w;
        v.h[4] = (_Float16)b.x; v.h[5] = (_Float16)b.y;
        v.h[6] = (_Float16)b.z; v.h[7] = (_Float16)b.w;
        *(uint4*)(c0 + (size_t)row * K2 + c8) = v.u;
        int p0 = __builtin_amdgcn_cvt_pk_fp8_f32(a.x, a.y, 0, false);
        p0 = __builtin_amdgcn_cvt_pk_fp8_f32(a.z, a.w, p0, true);
        int p1 = __builtin_amdgcn_cvt_pk_fp8_f32(b.x, b.y, 0, false);
        p1 = __builtin_amdgcn_cvt_pk_fp8_f32(b.z, b.w, p1, true);
        *(uint2*)(f8 + (size_t)row * HD + c8) = make_uint2((unsigned)p0, (unsigned)p1);
        return;
    }
    gi -= 800000;
    if (gi < 3 * HD * K2) {   // weights: transpose+concat -> fp16 [l][n][k]
        int t = (int)gi;
        int l = t / (HD * K2), r = t % (HD * K2);
        int n = r / K2, k = r % K2;
        const float* Ws = (l == 0) ? Ws0 : (l == 1) ? Ws1 : Ws2;
        const float* Wn = (l == 0) ? Wn0 : (l == 1) ? Wn1 : Wn2;
        float w = (k < HD) ? Ws[k * HD + n] : Wn[(k - HD) * HD + n];
        union { unsigned short u; _Float16 h; } c;
        c.h = (_Float16)w;
        wt[t] = c.u;
        return;
    }
    gi -= 3 * HD * K2;
    if (gi < N_GRAPHS * HD) { pooled[gi] = 0.f; return; }
    gi -= (long long)N_GRAPHS * HD;
    if (gi < N_GRAPHS) {   // graph counts via binary search (gid sorted)
        int g = (int)gi;
        int lo = 0, hi = N_NODES;
        while (lo < hi) { int mid = (lo + hi) >> 1; if (gid[mid] < g) lo = mid + 1; else hi = mid; }
        int start = lo;
        lo = 0; hi = N_NODES;
        while (lo < hi) { int mid = (lo + hi) >> 1; if (gid[mid] <= g) lo = mid + 1; else hi = mid; }
        counts[g] = (float)(lo - start);
    }
}

// ---------------- gather: one wave per node, fp8 rows, fp32 accum, 16 edges in flight ----------------
__global__ __launch_bounds__(256) void k_gather(const unsigned char* __restrict__ h8,
                                                const int* __restrict__ rowptr,
                                                const int* __restrict__ eidx,
                                                unsigned short* __restrict__ msg) {
    const int node = (blockIdx.x * 256 + threadIdx.x) >> 6;
    const int lane = threadIdx.x & 63;
    if (node >= N_NODES) return;
    const int epar = lane >> 4;        // 4 edge slots
    const int d0 = (lane & 15) * 8;    // 8 fp8 per lane = 8 B
    const int beg = rowptr[node], end = rowptr[node + 1];
    float acc[8] = {0.f, 0.f, 0.f, 0.f, 0.f, 0.f, 0.f, 0.f};
    int j = beg + epar;
    for (; j + 12 < end; j += 16) {    // 16 edges in flight per wave
        int s0 = eidx[j], s1 = eidx[j + 4], s2 = eidx[j + 8], s3 = eidx[j + 12];
        uint2 v0 = *(const uint2*)(h8 + (size_t)s0 * HD + d0);
        uint2 v1 = *(const uint2*)(h8 + (size_t)s1 * HD + d0);
        uint2 v2 = *(const uint2*)(h8 + (size_t)s2 * HD + d0);
        uint2 v3 = *(const uint2*)(h8 + (size_t)s3 * HD + d0);
        f32x2 e;
        e = __builtin_amdgcn_cvt_pk_f32_fp8(v0.x, false); acc[0] += e[0]; acc[1] += e[1];
        e = __builtin_amdgcn_cvt_pk_f32_fp8(v0.x, true);  acc[2] += e[0]; acc[3] += e[1];
        e = __builtin_amdgcn_cvt_pk_f32_fp8(v0.y, false); acc[4] += e[0]; acc[5] += e[1];
        e = __builtin_amdgcn_cvt_pk_f32_fp8(v0.y, true);  acc[6] += e[0]; acc[7] += e[1];
        e = __builtin_amdgcn_cvt_pk_f32_fp8(v1.x, false); acc[0] += e[0]; acc[1] += e[1];
        e = __builtin_amdgcn_cvt_pk_f32_fp8(v1.x, true);  acc[2] += e[0]; acc[3] += e[1];
        e = __builtin_amdgcn_cvt_pk_f32_fp8(v1.y, false); acc[4] += e[0]; acc[5] += e[1];
        e = __builtin_amdgcn_cvt_pk_f32_fp8(v1.y, true);  acc[6] += e[0]; acc[7] += e[1];
        e = __builtin_amdgcn_cvt_pk_f32_fp8(v2.x, false); acc[0] += e[0]; acc[1] += e[1];
        e = __builtin_amdgcn_cvt_pk_f32_fp8(v2.x, true);  acc[2] += e[0]; acc[3] += e[1];
        e = __builtin_amdgcn_cvt_pk_f32_fp8(v2.y, false); acc[4] += e[0]; acc[5] += e[1];
        e = __builtin_amdgcn_cvt_pk_f32_fp8(v2.y, true);  acc[6] += e[0]; acc[7] += e[1];
        e = __builtin_amdgcn_cvt_pk_f32_fp8(v3.x, false); acc[0] += e[0]; acc[1] += e[1];
        e = __builtin_amdgcn_cvt_pk_f32_fp8(v3.x, true);  acc[2] += e[0]; acc[3] += e[1];
        e = __builtin_amdgcn_cvt_pk_f32_fp8(v3.y, false); acc[4] += e[0]; acc[5] += e[1];
        e = __builtin_amdgcn_cvt_pk_f32_fp8(v3.y, true);  acc[6] += e[0]; acc[7] += e[1];
    }
    for (; j < end; j += 4) {
        uint2 v0 = *(const uint2*)(h8 + (size_t)eidx[j] * HD + d0);
        f32x2 e;
        e = __builtin_amdgcn_cvt_pk_f32_fp8(v0.x, false); acc[0] += e[0]; acc[1] += e[1];
        e = __builtin_amdgcn_cvt_pk_f32_fp8(v0.x, true);  acc[2] += e[0]; acc[3] += e[1];
        e = __builtin_amdgcn_cvt_pk_f32_fp8(v0.y, false); acc[4] += e[0]; acc[5] += e[1];
        e = __builtin_amdgcn_cvt_pk_f32_fp8(v0.y, true);  acc[6] += e[0]; acc[7] += e[1];
    }
#pragma unroll
    for (int i = 0; i < 8; ++i) {
        acc[i] += __shfl_xor(acc[i], 16);
        acc[i] += __shfl_xor(acc[i], 32);
    }
    if (epar == 0) {
        float inv = (end > beg) ? 1.0f / (float)(end - beg) : 0.f;
        U4H8 o;
#pragma unroll
        for (int i = 0; i < 8; ++i) o.h[i] = (_Float16)(acc[i] * inv);
        *(uint4*)(msg + (size_t)node * K2 + HD + d0) = o.u;
    }
}

// ---------------- SAGE layer: MFMA K=256; epilogue = write h/fp8 OR fused graph-pool ----------------
__global__ __launch_bounds__(256) void k_sage(const unsigned short* __restrict__ hin,  // [m][256] fp16
                                              const unsigned short* __restrict__ wt,   // [n][256] fp16
                                              const float* __restrict__ bias,
                                              unsigned short* __restrict__ hout,       // [m][256] h-part
                                              unsigned char* __restrict__ hout8,       // [m][128] fp8
                                              const int* __restrict__ gid,
                                              float* __restrict__ pooled,
                                              int write16, int dopool) {
    __shared__ __align__(16) _Float16 Ah[2][128 * 64];
    __shared__ __align__(16) _Float16 Bw[2][128 * 64];
    __shared__ float gpool[NSLOT][HD];
    __shared__ int ginfo[2];
    const int tid = threadIdx.x;
    const int wv = tid >> 6, lane = tid & 63;
    const int m0 = blockIdx.x * 128;
    const int m_off = (wv >> 1) * 64, n_off = (wv & 1) * 64;
    const int l15 = lane & 15, q = lane >> 4;

    f32x4 acc[4][4];
#pragma unroll
    for (int a = 0; a < 4; ++a)
#pragma unroll
        for (int b = 0; b < 4; ++b) acc[a][b] = (f32x4){0.f, 0.f, 0.f, 0.f};

    auto stage = [&](int bsel, int kt) {
        const int k0 = kt * 64;
#pragma unroll
        for (int i = 0; i < 4; ++i) {
            int idx = tid + i * 256;             // 1024 16B-chunks per operand tile
            int row = idx >> 3, c = idx & 7;
            int qs = (c ^ (row & 7)) * 8;        // pre-swizzled source chunk (halfs)
            int gm = m0 + row;
            if (gm < N_NODES)
                GLOAD_LDS16(hin + (size_t)gm * K2 + k0 + qs, &Ah[bsel][idx * 8]);
            GLOAD_LDS16(wt + (size_t)row * K2 + k0 + qs, &Bw[bsel][idx * 8]);
        }
    };

    stage(0, 0);
    __syncthreads();   // drains vmcnt(0): buf0 ready
#pragma unroll
    for (int kt = 0; kt < 4; ++kt) {
        const int b = kt & 1;
        if (kt < 3) stage(b ^ 1, kt + 1);        // prefetch next tile into other buffer
        f16x8 hf[4][2], wf[4][2];
#pragma unroll
        for (int mt = 0; mt < 4; ++mt) {
            const int row = m_off + mt * 16 + l15;
            const int sw = row & 7;
#pragma unroll
            for (int ks = 0; ks < 2; ++ks)
                hf[mt][ks] = *(const f16x8*)&Ah[b][row * 64 + (((ks * 4 + q) ^ sw) * 8)];
        }
#pragma unroll
        for (int nt = 0; nt < 4; ++nt) {
            const int row = n_off + nt * 16 + l15;
            const int sw = row & 7;
#pragma unroll
            for (int ks = 0; ks < 2; ++ks)
                wf[nt][ks] = *(const f16x8*)&Bw[b][row * 64 + (((ks * 4 + q) ^ sw) * 8)];
        }
#pragma unroll
        for (int mt = 0; mt < 4; ++mt)
#pragma unroll
            for (int nt = 0; nt < 4; ++nt) {
                acc[mt][nt] = __builtin_amdgcn_mfma_f32_16x16x32_f16(wf[nt][0], hf[mt][0], acc[mt][nt], 0, 0, 0);
                acc[mt][nt] = __builtin_amdgcn_mfma_f32_16x16x32_f16(wf[nt][1], hf[mt][1], acc[mt][nt], 0, 0, 0);
            }
        __syncthreads();
    }
    if (!dopool) {
#pragma unroll
        for (int nt = 0; nt < 4; ++nt) {
            int n = n_off + nt * 16 + q * 4;
            float4 bv = *(const float4*)(bias + n);
#pragma unroll
            for (int mt = 0; mt < 4; ++mt) {
                int m = m0 + m_off + mt * 16 + l15;
                if (m < N_NODES) {
                    f32x4 a = acc[mt][nt];
                    float r0 = fmaxf(a[0] + bv.x, 0.f);
                    float r1 = fmaxf(a[1] + bv.y, 0.f);
                    float r2 = fmaxf(a[2] + bv.z, 0.f);
                    float r3 = fmaxf(a[3] + bv.w, 0.f);
                    if (write16) {
                        U2H4 v;
                        v.h[0] = (_Float16)r0; v.h[1] = (_Float16)r1;
                        v.h[2] = (_Float16)r2; v.h[3] = (_Float16)r3;
                        *(uint2*)(hout + (size_t)m * K2 + n) = v.u;
                    }
                    int p = __builtin_amdgcn_cvt_pk_fp8_f32(r0, r1, 0, false);
                    p = __builtin_amdgcn_cvt_pk_fp8_f32(r2, r3, p, true);
                    *(unsigned int*)(hout8 + (size_t)m * HD + n) = (unsigned)p;
                }
            }
        }
    } else {
        // ---- fused graph mean-pool: LDS per-graph partials, then sparse flush ----
        for (int j = tid; j < NSLOT * HD; j += 256) ((float*)gpool)[j] = 0.f;
        if (tid == 0) {
            ginfo[0] = gid[m0];
            ginfo[1] = gid[min(m0 + 127, N_NODES - 1)];
        }
        __syncthreads();
        const int g_lo = ginfo[0];
        int gg[4];
#pragma unroll
        for (int mt = 0; mt < 4; ++mt) {
            int m = m0 + m_off + mt * 16 + l15;
            gg[mt] = (m < N_NODES) ? gid[m] : -1;
        }
#pragma unroll
        for (int nt = 0; nt < 4; ++nt) {
            int n = n_off + nt * 16 + q * 4;
            float4 bv = *(const float4*)(bias + n);
            int cur = -1;
            float p0 = 0.f, p1 = 0.f, p2 = 0.f, p3 = 0.f;
#pragma unroll
            for (int mt = 0; mt < 4; ++mt) {
                if (gg[mt] < 0) continue;
                f32x4 a = acc[mt][nt];
                float r0 = fmaxf(a[0] + bv.x, 0.f);
                float r1 = fmaxf(a[1] + bv.y, 0.f);
                float r2 = fmaxf(a[2] + bv.z, 0.f);
                float r3 = fmaxf(a[3] + bv.w, 0.f);
                if (gg[mt] != cur) {
                    if (cur >= 0) {
                        int s = cur - g_lo;
                        if (s < NSLOT) {
                            atomicAdd(&gpool[s][n], p0); atomicAdd(&gpool[s][n + 1], p1);
                            atomicAdd(&gpool[s][n + 2], p2); atomicAdd(&gpool[s][n + 3], p3);
                        } else {
                            atomicAdd(&pooled[(size_t)cur * HD + n], p0);
                            atomicAdd(&pooled[(size_t)cur * HD + n + 1], p1);
                            atomicAdd(&pooled[(size_t)cur * HD + n + 2], p2);
                            atomicAdd(&pooled[(size_t)cur * HD + n + 3], p3);
                        }
                    }
                    cur = gg[mt]; p0 = r0; p1 = r1; p2 = r2; p3 = r3;
                } else {
                    p0 += r0; p1 += r1; p2 += r2; p3 += r3;
                }
            }
            if (cur >= 0) {
                int s = cur - g_lo;
                if (s < NSLOT) {
                    atomicAdd(&gpool[s][n], p0); atomicAdd(&gpool[s][n + 1], p1);
                    atomicAdd(&gpool[s][n + 2], p2); atomicAdd(&gpool[s][n + 3], p3);
                } else {
                    atomicAdd(&pooled[(size_t)cur * HD + n], p0);
                    atomicAdd(&pooled[(size_t)cur * HD + n + 1], p1);
                    atomicAdd(&pooled[(size_t)cur * HD + n + 2], p2);
                    atomicAdd(&pooled[(size_t)cur * HD + n + 3], p3);
                }
            }
        }
        __syncthreads();
        const int nslot = min(NSLOT, ginfo[1] - g_lo + 1);
        for (int j = tid; j < nslot * HD; j += 256) {
            float v = gpool[j >> 7][j & 127];
            if (v != 0.f)
                atomicAdd(&pooled[(size_t)(g_lo + (j >> 7)) * HD + (j & 127)], v);
        }
    }
}

// ---------------- classifier (fp32) ----------------
__global__ __launch_bounds__(256) void k_final(const float* __restrict__ pooled,
                                               const float* __restrict__ counts,
                                               const float* __restrict__ Wf,
                                               const float* __restrict__ bf,
                                               float* __restrict__ out) {
    int t = blockIdx.x * 256 + threadIdx.x;
    if (t >= N_GRAPHS * CLS) return;
    int g = t / CLS, c = t % CLS;
    float inv = 1.0f / fmaxf(counts[g], 1.0f);
    float s = 0.f;
    for (int k = 0; k < HD; ++k) s += pooled[(size_t)g * HD + k] * Wf[k * CLS + c];
    out[t] = s * inv + bf[c];
}

extern "C" void kernel_launch(void* const* d_in, const int* in_sizes, int n_in,
                              void* d_out, int out_size, void* d_ws, size_t ws_size,
                              hipStream_t stream) {
    const float* features = (const float*)d_in[0];
    const int*   esrc     = (const int*)d_in[1];
    const int*   edst     = (const int*)d_in[2];
    const int*   gids     = (const int*)d_in[3];
    const float* bs[3]  = {(const float*)d_in[6], (const float*)d_in[9], (const float*)d_in[12]};
    const float* Wf = (const float*)d_in[13];
    const float* bfv = (const float*)d_in[14];
    float* out = (float*)d_out;

    int* gcount = (int*)d_ws;            // 8   \ zeroed together by k_zero (264 ints)
    int* bflag  = gcount + 8;            // 256 /
    int* bsum   = bflag + 256;           // 256 (written before flag release)
    int* rowptr = bsum + 256;            // 50001 (+pad)
    int* eidx   = rowptr + 50008;        // 800000
    unsigned* stag = (unsigned*)(eidx + 800000);
    int* ghist  = (int*)(stag + (size_t)NPART * PCAP);   // 128 planes x 6250
    float* pooled = (float*)(ghist + (size_t)NPART * NSUB * PSIZE);
    float* counts = pooled + N_GRAPHS * HD;
    unsigned short* C0 = (unsigned short*)(counts + 128);    // 50000*256 fp16 x3 (h|msg)
    unsigned short* C1 = C0 + (size_t)N_NODES * K2;
    unsigned short* C2 = C1 + (size_t)N_NODES * K2;
    unsigned short* Wt = C2 + (size_t)N_NODES * K2;
    unsigned char* F0 = (unsigned char*)(Wt + 3 * HD * K2);
    unsigned char* F1 = F0 + (size_t)N_NODES * HD;
    unsigned char* F2 = F1 + (size_t)N_NODES * HD;

    k_zero<<<1, 512, 0, stream>>>(gcount);

    k_bin<<<NBIN, 256, 0, stream>>>(esrc, edst, stag, gcount);
    k_hist<<<NPART * NSUB, 512, 0, stream>>>(stag, gcount, ghist);
    k_scan<<<NB_SCAN, 256, 0, stream>>>(ghist, rowptr, bsum, bflag);
    k_scatterinit<<<128 + INIT_BLOCKS5, 512, 0, stream>>>(
        stag, gcount, ghist, eidx,
        features, C0, F0,
        (const float*)d_in[4], (const float*)d_in[5],
        (const float*)d_in[7], (const float*)d_in[8],
        (const float*)d_in[10], (const float*)d_in[11],
        Wt, pooled, gids, counts);

    unsigned short* C[4] = {C0, C1, C2, C0};
    unsigned char* F[4] = {F0, F1, F2, F0};
    for (int l = 0; l < 3; ++l) {
        k_gather<<<(N_NODES * 64 + 255) / 256, 256, 0, stream>>>(F[l], rowptr, eidx, C[l]);
        k_sage<<<(N_NODES + 127) / 128, 256, 0, stream>>>(
            C[l], Wt + (size_t)l * HD * K2, bs[l], C[l + 1], F[l + 1],
            gids, pooled, (l < 2) ? 1 : 0, (l == 2) ? 1 : 0);
    }

    k_final<<<(N_GRAPHS * CLS + 255) / 256, 256, 0, stream>>>(pooled, counts, Wf, bfv, out);
}